// Round 13
// baseline (77.503 us; speedup 1.0000x reference)
//
#include <hip/hip_runtime.h>
#include <hip/hip_bf16.h>

// out[b,h,w,dy*9+dx] = leaky_relu( mean_c( prv[b,h,w,c] * nxt[b,h+dy-4,w+dx-4,c] ), 0.1 )
// R13: R12's verified 16x16 banded-MFMA core, re-structured for pipe utilization:
//  - 1024 thr / 16 waves, 1 output row per wave -> acc 72 f32, VGPR<=128 (lb 1024,4)
//    => 16 waves/CU (R12 was 8: 256-reg threads -> 1 block).
//  - double-buffered LDS (2x53.4KB), ONE non-draining barrier per kstep:
//    loads for k+1 issued pre-barrier, in flight through compute(k) (coalesced-regime
//    retry of the R6 mechanism).
//  - staging: 4ch granule = 16B dwordx4/lane, [pixel][c8] order (R10-verified, ~16
//    lines/wave-load); LDS granule-major odd stride (conflict-light, R12: 1.5M).

#define B_ 8
#define H_ 128
#define W_ 128
#define C_ 192
#define ND 9
#define NDISP 81
#define HT 16           // tile rows
#define WT 16           // tile cols
#define KS 32           // channels per k-step
#define NK 6            // 192/32
#define BROWS 24        // HT+8 staged nxt rows
#define BCOLS 24        // WT+8 staged nxt cols
#define APIX (HT * WT)         // 256
#define BPIX (BROWS * BCOLS)   // 576
#define ASTR 257               // odd 8B-slot stride (granule-major) for A
#define BSTR 577               // odd stride for B
#define ASLOTS (8 * ASTR)      // 2056
#define BSLOTS (8 * BSTR)      // 4616
#define NSA 2                  // A granule-slots per thread (256*8/1024)
#define NSB 5                  // B granule-slots per thread (ceil(576*8/1024)); slot 4: tid<512

typedef short short8 __attribute__((ext_vector_type(8)));
typedef short short4_t __attribute__((ext_vector_type(4)));
typedef float f32x4 __attribute__((ext_vector_type(4)));

static __device__ __forceinline__ short bf1(float f) {
    __hip_bfloat16 h = __float2bfloat16(f);   // pairs fuse to v_cvt_pk_bf16_f32
    return __builtin_bit_cast(short, h);
}

static __device__ __forceinline__ short4_t cvt4(float4 v) {
    short4_t r;
    r[0] = bf1(v.x); r[1] = bf1(v.y); r[2] = bf1(v.z); r[3] = bf1(v.w);
    return r;
}

static __device__ __forceinline__ short8 cat(short4_t u, short4_t v) {
    return __builtin_shufflevector(u, v, 0, 1, 2, 3, 4, 5, 6, 7);
}

// LDS-fence + barrier WITHOUT vmcnt drain: outstanding global loads stay in flight.
static __device__ __forceinline__ void barrier_no_vm_drain() {
    asm volatile("s_waitcnt lgkmcnt(0)\n\ts_barrier" ::: "memory");
}

__global__ __launch_bounds__(1024, 4)
void cv_mfma(const float* __restrict__ prv, const float* __restrict__ nxt,
             float* __restrict__ out) {
    __shared__ short4_t sm[2][ASLOTS + BSLOTS];   // 2 x 53.4 KB

    const int tid = threadIdx.x;
    const int w0 = blockIdx.x * WT;
    const int h0 = blockIdx.y * HT;
    const int b  = blockIdx.z;

    const int lane = tid & 63;
    const int wid  = tid >> 6;      // 0..15: wave owns output row h0+wid
    const int lq = lane & 15;
    const int lc = lane >> 4;

    const int tp = tid >> 3;        // 0..127: pixel sub-index for staging
    const int c8 = tid & 7;         // 0..7: 4-channel granule within k-step

    // ---- hoisted global element-offsets (k-step adds ks*KS)
    int aoff[NSA];
#pragma unroll
    for (int i = 0; i < NSA; ++i) {
        const int p = tp + 128 * i;        // 0..255
        const int r = p >> 4;
        const int pc = p & 15;
        aoff[i] = ((b * H_ + h0 + r) * W_ + w0 + pc) * C_ + c8 * 4;
    }
    int boff[NSB];
    unsigned bmask = 0;
#pragma unroll
    for (int i = 0; i < NSB; ++i) {
        const int p = tp + 128 * i;        // 0..639; slot 4 valid only p<576
        const int row = p / BCOLS;
        const int col = p - row * BCOLS;
        const int gh = h0 - 4 + row;
        const int gw = w0 - 4 + col;
        const bool inb = (p < BPIX) && ((unsigned)gh < (unsigned)H_) && ((unsigned)gw < (unsigned)W_);
        if (inb) bmask |= (1u << i);
        boff[i] = ((b * H_ + (inb ? gh : 0)) * W_ + (inb ? gw : 0)) * C_ + c8 * 4;
    }
    const bool wr4 = (tid < 512);   // slot-4 LDS write coverage (p<576), wave-uniform

    // ---- staging registers (live across one barrier)
    float4 xa[NSA], xb[NSB];

    // prologue: issue loads for kstep 0
#pragma unroll
    for (int i = 0; i < NSA; ++i) xa[i] = *(const float4*)(prv + aoff[i]);
#pragma unroll
    for (int i = 0; i < NSB; ++i) {
        xb[i] = make_float4(0.f, 0.f, 0.f, 0.f);
        if (bmask & (1u << i)) xb[i] = *(const float4*)(nxt + boff[i]);
    }

    f32x4 acc[ND][2];
#pragma unroll
    for (int d = 0; d < ND; ++d) {
        acc[d][0] = (f32x4){0.f, 0.f, 0.f, 0.f};
        acc[d][1] = (f32x4){0.f, 0.f, 0.f, 0.f};
    }

    for (int it = 0; it < NK; ++it) {
        short4_t* sA = sm[it & 1];
        short4_t* sB = sm[it & 1] + ASLOTS;

        // ---- cvt + write kstep `it` (vmcnt waits for xa/xb inserted here)
#pragma unroll
        for (int i = 0; i < NSA; ++i)
            sA[c8 * ASTR + tp + 128 * i] = cvt4(xa[i]);
#pragma unroll
        for (int i = 0; i < NSB - 1; ++i)
            sB[c8 * BSTR + tp + 128 * i] = cvt4(xb[i]);
        if (wr4)
            sB[c8 * BSTR + tp + 128 * (NSB - 1)] = cvt4(xb[NSB - 1]);

        // ---- issue kstep it+1 loads; stay in flight across barrier + compute
        if (it + 1 < NK) {
            const int co = (it + 1) * KS;
#pragma unroll
            for (int i = 0; i < NSA; ++i) xa[i] = *(const float4*)(prv + aoff[i] + co);
#pragma unroll
            for (int i = 0; i < NSB; ++i) {
                if (bmask & (1u << i)) xb[i] = *(const float4*)(nxt + boff[i] + co);
            }
        }

        barrier_no_vm_drain();   // LDS writes visible; global loads NOT drained

        // ---- compute: wave's row vs 9 dy x 2 col-tiles
        const int pA = wid * WT + lq;
        const short8 a = cat(sA[2 * lc * ASTR + pA], sA[(2 * lc + 1) * ASTR + pA]);
#pragma unroll
        for (int dy = 0; dy < ND; ++dy) {
            const int pB = (wid + dy) * BCOLS + lq;
            const short8 b0 = cat(sB[2 * lc * BSTR + pB],     sB[(2 * lc + 1) * BSTR + pB]);
            const short8 b1 = cat(sB[2 * lc * BSTR + pB + 8], sB[(2 * lc + 1) * BSTR + pB + 8]);
            acc[dy][0] = __builtin_amdgcn_mfma_f32_16x16x32_bf16(a, b0, acc[dy][0], 0, 0, 0);
            acc[dy][1] = __builtin_amdgcn_mfma_f32_16x16x32_bf16(a, b1, acc[dy][1], 0, 0, 0);
        }
        // single barrier per kstep is race-free: writes of it+1 target the OTHER
        // buffer, and a wave can't reach writes of it+2 (same buffer as `it`)
        // without passing barrier it+1, which requires all waves done computing `it`.
    }

    // ---- epilogue (R5/R10/R12-verified): D col=lane&15 (q), D row=4*lc+rg (rD=w-pos).
    // rows rD<8 from tile0 (dx=q-rD), rD>=8 from tile1 (dx=q-rD+8); exclusive+complete.
    const float inv = 1.0f / (float)C_;
    const int h = h0 + wid;
    if (lc < 2) {
#pragma unroll
        for (int rg = 0; rg < 4; ++rg) {
            const int r = 4 * lc + rg;
            const int dx = lq - r;
            if (dx >= 0 && dx <= 8) {
                float* o = out + (size_t)((b * H_ + h) * W_ + w0 + r) * NDISP + dx;
#pragma unroll
                for (int dy = 0; dy < ND; ++dy) {
                    const float v = acc[dy][0][rg] * inv;
                    o[dy * ND] = v >= 0.f ? v : 0.1f * v;
                }
            }
        }
    } else {
#pragma unroll
        for (int rg = 0; rg < 4; ++rg) {
            const int r = 4 * lc + rg;       // 8..15
            const int dx = lq - r + 8;
            if (dx >= 0 && dx <= 8) {
                float* o = out + (size_t)((b * H_ + h) * W_ + w0 + r) * NDISP + dx;
#pragma unroll
                for (int dy = 0; dy < ND; ++dy) {
                    const float v = acc[dy][1][rg] * inv;
                    o[dy * ND] = v >= 0.f ? v : 0.1f * v;
                }
            }
        }
    }
}

extern "C" void kernel_launch(void* const* d_in, const int* in_sizes, int n_in,
                              void* d_out, int out_size, void* d_ws, size_t ws_size,
                              hipStream_t stream) {
    const float* prv = (const float*)d_in[0];
    const float* nxt = (const float*)d_in[1];
    float* out = (float*)d_out;

    dim3 grid(W_ / WT, H_ / HT, B_);   // (8, 8, 8) = 512 blocks x 1024 threads
    cv_mfma<<<grid, 1024, 0, stream>>>(prv, nxt, out);
}